// Round 16
// baseline (318.373 us; speedup 1.0000x reference)
//
#include <hip/hip_runtime.h>
#include <hip/hip_bf16.h>

typedef __hip_bfloat16 hbf16;
typedef unsigned int u32;
typedef __attribute__((ext_vector_type(2))) float f32x2;
typedef __attribute__((ext_vector_type(8))) short bf16x8;
typedef __attribute__((ext_vector_type(4))) float f32x4;

__device__ __forceinline__ f32x2 bf2pair(u32 v) {
  f32x2 o;
  o[0] = __uint_as_float(v << 16);
  o[1] = __uint_as_float(v & 0xffff0000u);
  return o;
}

// ---- packed f32 VOP3P helpers (NOTE: no v_pk_max_f32 on gfx950!) ----
__device__ __forceinline__ f32x2 pk_add(f32x2 a, f32x2 b) {
  f32x2 d; asm("v_pk_add_f32 %0, %1, %2" : "=v"(d) : "v"(a), "v"(b)); return d;
}
__device__ __forceinline__ f32x2 pk_mul(f32x2 a, f32x2 b) {
  f32x2 d; asm("v_pk_mul_f32 %0, %1, %2" : "=v"(d) : "v"(a), "v"(b)); return d;
}
__device__ __forceinline__ f32x2 pk_fma(f32x2 a, f32x2 b, f32x2 c) {
  f32x2 d; asm("v_pk_fma_f32 %0, %1, %2, %3" : "=v"(d) : "v"(a), "v"(b), "v"(c)); return d;
}
__device__ __forceinline__ f32x2 pk_fma_b0(f32x2 a, f32x2 b, f32x2 c) {
  f32x2 d;
  asm("v_pk_fma_f32 %0, %1, %2, %3 op_sel:[0,0,0] op_sel_hi:[1,0,1]"
      : "=v"(d) : "v"(a), "v"(b), "v"(c));
  return d;
}
__device__ __forceinline__ f32x2 pk_fma_b1(f32x2 a, f32x2 b, f32x2 c) {
  f32x2 d;
  asm("v_pk_fma_f32 %0, %1, %2, %3 op_sel:[0,1,0] op_sel_hi:[1,1,1]"
      : "=v"(d) : "v"(a), "v"(b), "v"(c));
  return d;
}
__device__ __forceinline__ f32x2 pk_mul_b0(f32x2 a, f32x2 b) {
  f32x2 d;
  asm("v_pk_mul_f32 %0, %1, %2 op_sel:[0,0] op_sel_hi:[1,0]"
      : "=v"(d) : "v"(a), "v"(b));
  return d;
}

// ---- DPP butterfly add steps (pure VALU, no DS) ----
template <int CTRL>
__device__ __forceinline__ float dpp_add(float p) {
  int t = __builtin_amdgcn_update_dpp(0, __float_as_int(p), CTRL, 0xF, 0xF, true);
  return p + __int_as_float(t);
}
// xor16 within 32-lane group via ds_swizzle bit-mode (no addr calc)
__device__ __forceinline__ float swz_add16(float p) {
  int t = __builtin_amdgcn_ds_swizzle(__float_as_int(p), 0x401F);
  return p + __int_as_float(t);
}

__device__ __forceinline__ void storeO(float* p, float v) { *p = v; }
__device__ __forceinline__ void storeO(hbf16* p, float v) { *p = __float2bfloat16(v); }

// ---------------- prep: hist + cvt(x) + 5 weight transposes, one launch ----------
__device__ __forceinline__ void tcvt_dev(const float* __restrict__ W,
                                         hbf16* __restrict__ Wt, int K, int N,
                                         int b, int tid, hbf16 (*tile)[33]) {
  const int nb32 = N >> 5;
  const int n0 = (b % nb32) << 5, k0 = (b / nb32) << 5;
  const int tx = tid & 31, ty = tid >> 5;
#pragma unroll
  for (int i = 0; i < 4; ++i)
    tile[ty * 4 + i][tx] = __float2bfloat16(W[(size_t)(k0 + ty * 4 + i) * N + n0 + tx]);
  __syncthreads();
#pragma unroll
  for (int i = 0; i < 4; ++i)
    Wt[(size_t)(n0 + ty * 4 + i) * K + k0 + tx] = tile[tx][ty * 4 + i];
}

__global__ __launch_bounds__(256) void prep_hist_kernel(
    const int* __restrict__ dst, int* __restrict__ P, int E, int eB,
    const float* __restrict__ x, hbf16* __restrict__ xb, int n, int nxB,
    const float* __restrict__ W1l, hbf16* __restrict__ W1lt,
    const float* __restrict__ W1r, hbf16* __restrict__ W1rt,
    const float* __restrict__ W2l, hbf16* __restrict__ W2lt,
    const float* __restrict__ W2r, hbf16* __restrict__ W2rt,
    const float* __restrict__ Wp, hbf16* __restrict__ Wpt) {
  __shared__ hbf16 tile[32][33];
  int b = blockIdx.x;
  const int tid = threadIdx.x;
  if (b < eB) {
    int i = b * 256 + tid;
    if (i < E) atomicAdd(&P[dst[i]], 1);
    return;
  }
  b -= eB;
  if (b < nxB) {
    int i = (b * 256 + tid) * 4;
    if (i < n) {
      float4 v = *(const float4*)(x + i);
      xb[i] = __float2bfloat16(v.x);
      xb[i + 1] = __float2bfloat16(v.y);
      xb[i + 2] = __float2bfloat16(v.z);
      xb[i + 3] = __float2bfloat16(v.w);
    }
    return;
  }
  b -= nxB;
  if (b < 64) { tcvt_dev(W1l, W1lt, 256, 256, b, tid, tile); return; }
  b -= 64;
  if (b < 64) { tcvt_dev(W1r, W1rt, 256, 256, b, tid, tile); return; }
  b -= 64;
  if (b < 256) { tcvt_dev(W2l, W2lt, 256, 1024, b, tid, tile); return; }
  b -= 256;
  if (b < 256) { tcvt_dev(W2r, W2rt, 256, 1024, b, tid, tile); return; }
  b -= 256;
  tcvt_dev(Wp, Wpt, 1024, 256, b, tid, tile);
}

// ---- MFMA GEMM body (device): C[M,N] = A@Bt^T + dual bias, reg-dbuf k-pipeline ----
template <typename OutT>
__device__ __forceinline__ void gemm_body(
    int bx, int by, const hbf16* __restrict__ A, const hbf16* __restrict__ Bt,
    const float* __restrict__ bias0, const float* __restrict__ bias1, int NS,
    OutT* __restrict__ C, int M, int N, int K) {
  const int tid = threadIdx.x, lane = tid & 63, w = tid >> 6;
  const int wr = w >> 1, wc = w & 1;
  const int rowb = by * 128 + wr * 64;
  const int colb = bx * 128 + wc * 64;
  const int lr = lane & 15, lk = (lane >> 4) * 8;

  f32x4 acc[4][4];
#pragma unroll
  for (int mi = 0; mi < 4; ++mi)
#pragma unroll
    for (int ni = 0; ni < 4; ++ni) acc[mi][ni] = {0.f, 0.f, 0.f, 0.f};

  const short* Ap = (const short*)A;
  const short* Bp = (const short*)Bt;

  int ar[4];
#pragma unroll
  for (int mi = 0; mi < 4; ++mi) {
    int r = rowb + mi * 16 + lr;
    ar[mi] = (r < M) ? r : (M - 1);  // clamp: garbage rows never stored
  }

  bf16x8 afC[4], bfC[4];
#pragma unroll
  for (int mi = 0; mi < 4; ++mi)
    afC[mi] = *(const bf16x8*)(Ap + (size_t)ar[mi] * K + lk);
#pragma unroll
  for (int ni = 0; ni < 4; ++ni)
    bfC[ni] = *(const bf16x8*)(Bp + (size_t)(colb + ni * 16 + lr) * K + lk);

  for (int k0 = 0; k0 < K; k0 += 32) {
    bf16x8 afN[4], bfN[4];
    const int kn = k0 + 32;
    if (kn < K) {
#pragma unroll
      for (int mi = 0; mi < 4; ++mi)
        afN[mi] = *(const bf16x8*)(Ap + (size_t)ar[mi] * K + kn + lk);
#pragma unroll
      for (int ni = 0; ni < 4; ++ni)
        bfN[ni] = *(const bf16x8*)(Bp + (size_t)(colb + ni * 16 + lr) * K + kn + lk);
    }
#pragma unroll
    for (int mi = 0; mi < 4; ++mi)
#pragma unroll
      for (int ni = 0; ni < 4; ++ni)
        acc[mi][ni] = __builtin_amdgcn_mfma_f32_16x16x32_bf16(afC[mi], bfC[ni],
                                                              acc[mi][ni], 0, 0, 0);
#pragma unroll
    for (int mi = 0; mi < 4; ++mi) afC[mi] = afN[mi];
#pragma unroll
    for (int ni = 0; ni < 4; ++ni) bfC[ni] = bfN[ni];
  }

  float bv[4];
#pragma unroll
  for (int ni = 0; ni < 4; ++ni) {
    int gc = colb + ni * 16 + lr;
    bv[ni] = (gc < NS) ? bias0[gc] : bias1[gc - NS];
  }
#pragma unroll
  for (int mi = 0; mi < 4; ++mi) {
    const int row0 = rowb + mi * 16 + (lane >> 4) * 4;
#pragma unroll
    for (int r = 0; r < 4; ++r) {
      const int row = row0 + r;
      if (row >= M) continue;
#pragma unroll
      for (int ni = 0; ni < 4; ++ni)
        storeO(&C[(size_t)row * N + colb + ni * 16 + lr], acc[mi][ni][r] + bv[ni]);
    }
  }
}

template <typename OutT>
__global__ __launch_bounds__(256) void mfma_gemm_kernel(
    const hbf16* __restrict__ A, const hbf16* __restrict__ Bt,
    const float* __restrict__ bias0, const float* __restrict__ bias1, int NS,
    OutT* __restrict__ C, int M, int N, int K) {
  gemm_body<OutT>(blockIdx.x, blockIdx.y, A, Bt, bias0, bias1, NS, C, M, N, K);
}

// ---------------- CSR scan (2 launches) ----------------
__global__ __launch_bounds__(256) void scan_sum_kernel(const int* __restrict__ P,
                                                       int* __restrict__ part, int n) {
  __shared__ int s[256];
  int i = blockIdx.x * 256 + threadIdx.x;
  s[threadIdx.x] = (i < n) ? P[i] : 0;
  __syncthreads();
#pragma unroll
  for (int off = 128; off; off >>= 1) {
    if (threadIdx.x < off) s[threadIdx.x] += s[threadIdx.x + off];
    __syncthreads();
  }
  if (threadIdx.x == 0) part[blockIdx.x] = s[0];
}

// each block redundantly scans the (<=256) raw partials, then scans its chunk
__global__ __launch_bounds__(256) void scan_apply_kernel(int* __restrict__ P,
                                                         const int* __restrict__ part,
                                                         int n, int nb) {
  __shared__ int sp[256];
  __shared__ int s[256];
  int pv = (threadIdx.x < nb) ? part[threadIdx.x] : 0;
  sp[threadIdx.x] = pv;
  __syncthreads();
#pragma unroll
  for (int off = 1; off < 256; off <<= 1) {
    int t = (threadIdx.x >= off) ? sp[threadIdx.x - off] : 0;
    __syncthreads();
    sp[threadIdx.x] += t;
    __syncthreads();
  }
  const int boff = (blockIdx.x == 0) ? 0 : sp[blockIdx.x - 1];
  int i = blockIdx.x * 256 + threadIdx.x;
  int v = (i < n) ? P[i] : 0;
  s[threadIdx.x] = v;
  __syncthreads();
#pragma unroll
  for (int off = 1; off < 256; off <<= 1) {
    int t = (threadIdx.x >= off) ? s[threadIdx.x - off] : 0;
    __syncthreads();
    s[threadIdx.x] += t;
    __syncthreads();
  }
  if (i < n) P[i] = s[threadIdx.x] - v + boff;
}

// ---------------- scatter + GEMM1 merged ----------------
__global__ __launch_bounds__(256) void scatter_gemm1_kernel(
    const int* __restrict__ dst, int* __restrict__ P, int* __restrict__ perm,
    int E, int eB,
    const hbf16* __restrict__ A, const hbf16* __restrict__ Bt,
    const float* __restrict__ bias0, const float* __restrict__ bias1,
    hbf16* __restrict__ C, int M) {
  if ((int)blockIdx.x < eB) {
    int i = blockIdx.x * 256 + threadIdx.x;
    if (i < E) {
      int pos = atomicAdd(&P[dst[i]], 1);
      perm[pos] = i;
    }
    return;
  }
  const int b = blockIdx.x - eB;
  gemm_body<hbf16>(b & 3, b >> 2, A, Bt, bias0, bias1, 256, C, M, 512, 256);
}

// ---------------- alpha + projector GEMM merged ----------------
__global__ __launch_bounds__(256) void alpha_gemmp_kernel(
    float* __restrict__ la, const float2* __restrict__ msbuf,
    const int* __restrict__ dst, int n4, int gp,
    const hbf16* __restrict__ A, const hbf16* __restrict__ Bt,
    const float* __restrict__ bias, float* __restrict__ C, int M) {
  if ((int)blockIdx.x < gp) {
    gemm_body<float>(blockIdx.x & 1, blockIdx.x >> 1, A, Bt, bias, bias, 256, C,
                     M, 256, 1024);
    return;
  }
  int i = (blockIdx.x - gp) * 256 + threadIdx.x;
  if (i >= n4) return;
  int e = i >> 2, h = i & 3;
  int d = dst[e];
  float2 ms = msbuf[d * 4 + h];
  la[i] = __expf(la[i] - ms.x) / ms.y;
}

// ---------------- fused GATv2 layer 1: TWO WAVES PER NODE (PAIRS=2, CPT=4) --------
// Wave pair splits the edge list in alternating 64-edge chunks; independent
// online-softmax state; associative LDS merge. 2 nodes / 256-thread block.
__global__ __launch_bounds__(256) void fused_gat_l1_kernel(
    const hbf16* __restrict__ xl, const hbf16* __restrict__ xr, int ldx,
    const float* __restrict__ ea, const float* __restrict__ We,
    const float* __restrict__ att, const int* __restrict__ src,
    const int* __restrict__ Pend, const int* __restrict__ perm,
    const float* __restrict__ bias, hbf16* __restrict__ out, int NN) {
  constexpr int PAIRS = 2, HC = 256;
  const int lane = threadIdx.x & 63;
  const int wv = threadIdx.x >> 6;      // 0..3
  const int slot = wv >> 1;             // node slot in block
  const int win = wv & 1;               // wave within node
  const int d = blockIdx.x * 2 + slot;
  __shared__ float4 s_ef[4][64];
  __shared__ f32x2 accS[4][PAIRS][64];
  __shared__ float msS[4][2][64];
  const bool valid = (d < NN);
  const int beg = (valid && d > 0) ? Pend[d - 1] : 0;
  const int end = valid ? Pend[d] : 0;
  const int j0 = lane * 4;

  f32x2 w0p[PAIRS], w1p[PAIRS], w2p[PAIRS], atp[PAIRS], xrp[PAIRS];
  if (valid) {
    u32 xraw[PAIRS];
    *(uint2*)xraw = *(const uint2*)((const u32*)((const short*)xr + (size_t)d * ldx + j0));
#pragma unroll
    for (int k = 0; k < PAIRS; ++k) {
      xrp[k] = bf2pair(xraw[k]);
      w0p[k] = *(const f32x2*)(We + j0 + 2 * k);
      w1p[k] = *(const f32x2*)(We + HC + j0 + 2 * k);
      w2p[k] = *(const f32x2*)(We + 2 * HC + j0 + 2 * k);
      atp[k] = *(const f32x2*)(att + j0 + 2 * k);
    }
  }
  f32x2 p02;
  p02[0] = 0.2f; p02[1] = 0.2f;

  float m_run = -INFINITY, ssum = 0.f;
  f32x2 accp[PAIRS];
#pragma unroll
  for (int k = 0; k < PAIRS; ++k) accp[k] = {0.f, 0.f};

  const short* xls = (const short*)xl;

#define LOADR1(R, IDX)                                                          \
  {                                                                             \
    int s_ = __builtin_amdgcn_readlane(sv, (IDX));                              \
    *(uint2*)(R) = *(const uint2*)((const u32*)(xls + (size_t)s_ * ldx + j0));  \
  }

#define DOT1(R, E01, E22, XV, POUT)                                            \
  {                                                                            \
    f32x2 q2 = {0.f, 0.f};                                                     \
    _Pragma("unroll") for (int k = 0; k < PAIRS; ++k) {                        \
      (XV)[k] = bf2pair((R)[k]);                                               \
      f32x2 u = pk_add((XV)[k], xrp[k]);                                       \
      u = pk_fma_b0(w0p[k], (E01), u);                                         \
      u = pk_fma_b1(w1p[k], (E01), u);                                         \
      u = pk_fma(w2p[k], (E22), u);                                            \
      f32x2 t = pk_mul(u, p02);                                                \
      f32x2 l;                                                                 \
      l[0] = fmaxf(u[0], t[0]);                                                \
      l[1] = fmaxf(u[1], t[1]);                                                \
      q2 = pk_fma(l, atp[k], q2);                                              \
    }                                                                          \
    (POUT) = q2[0] + q2[1];                                                    \
  }

#define SMUP1(P, XV)                                                           \
  {                                                                            \
    if (__any((P) > m_run)) {                                                  \
      const float nm = fmaxf(m_run, (P));                                      \
      const float sc = __expf(m_run - nm);                                     \
      ssum *= sc;                                                              \
      f32x2 scp; scp[0] = sc; scp[1] = sc;                                     \
      _Pragma("unroll") for (int k = 0; k < PAIRS; ++k)                        \
          accp[k] = pk_mul_b0(accp[k], scp);                                   \
      m_run = nm;                                                              \
    }                                                                          \
    const float pe = __expf((P) - m_run);                                      \
    ssum += pe;                                                                \
    f32x2 pep; pep[0] = pe; pep[1] = pe;                                       \
    _Pragma("unroll") for (int k = 0; k < PAIRS; ++k)                          \
        accp[k] = pk_fma_b0((XV)[k], pep, accp[k]);                            \
  }

#define PROC1(RA, RB, IBASE)                                                   \
  {                                                                            \
    const int iA = (IBASE), iB = (IBASE) + 1;                                  \
    const float4 efA = s_ef[wv][iA];                                           \
    const float4 efB = s_ef[wv][iB];                                           \
    f32x2 eA01, eA22, eB01, eB22;                                              \
    eA01[0] = efA.x; eA01[1] = efA.y; eA22[0] = efA.z; eA22[1] = efA.w;        \
    eB01[0] = efB.x; eB01[1] = efB.y; eB22[0] = efB.z; eB22[1] = efB.w;        \
    f32x2 xvA[PAIRS], xvB[PAIRS];                                              \
    float pA, pB;                                                              \
    DOT1(RA, eA01, eA22, xvA, pA);                                             \
    DOT1(RB, eB01, eB22, xvB, pB);                                             \
    LOADR1(RA, min(iA + 4, nbm1));                                             \
    LOADR1(RB, min(iB + 4, nbm1));                                             \
    pA = dpp_add<0xB1>(pA);  pB = dpp_add<0xB1>(pB);                           \
    pA = dpp_add<0x4E>(pA);  pB = dpp_add<0x4E>(pB);                           \
    pA = dpp_add<0x141>(pA); pB = dpp_add<0x141>(pB);                          \
    pA = dpp_add<0x140>(pA); pB = dpp_add<0x140>(pB);                          \
    SMUP1(pA, xvA);                                                            \
    SMUP1(pB, xvB);                                                            \
  }

#define TAIL1(R, I)                                                            \
  {                                                                            \
    const float4 ef = s_ef[wv][I];                                             \
    f32x2 e01, e22;                                                            \
    e01[0] = ef.x; e01[1] = ef.y; e22[0] = ef.z; e22[1] = ef.w;                \
    f32x2 xv[PAIRS];                                                           \
    float p;                                                                   \
    DOT1(R, e01, e22, xv, p);                                                  \
    p = dpp_add<0xB1>(p);                                                      \
    p = dpp_add<0x4E>(p);                                                      \
    p = dpp_add<0x141>(p);                                                     \
    p = dpp_add<0x140>(p);                                                     \
    SMUP1(p, xv);                                                              \
  }

  // alternating 64-edge chunks between the node's two waves
  for (int base = beg + win * 64; base < end; base += 128) {
    const int nb = min(64, end - base);
    const int nbm1 = nb - 1;
    const int nb4 = nb & ~3;
    int sv = 0;
    if (lane < nb) {
      int eid = perm[base + lane];
      sv = src[eid];
      float a0 = ea[3 * (size_t)eid], a1 = ea[3 * (size_t)eid + 1],
            a2 = ea[3 * (size_t)eid + 2];
      s_ef[wv][lane] = make_float4(a0, a1, a2, a2);
    }
    asm volatile("s_waitcnt lgkmcnt(0)" ::: "memory");

    u32 r0[PAIRS], r1[PAIRS], r2[PAIRS], r3[PAIRS];
    LOADR1(r0, 0);
    LOADR1(r1, min(1, nbm1));
    LOADR1(r2, min(2, nbm1));
    LOADR1(r3, min(3, nbm1));

    for (int i = 0; i < nb4; i += 4) {
      PROC1(r0, r1, i);
      PROC1(r2, r3, i + 2);
    }
    if (nb4 + 0 < nb) TAIL1(r0, nb4 + 0);
    if (nb4 + 1 < nb) TAIL1(r1, nb4 + 1);
    if (nb4 + 2 < nb) TAIL1(r2, nb4 + 2);
  }
#undef LOADR1
#undef DOT1
#undef SMUP1
#undef PROC1
#undef TAIL1

  // merge the two waves' states (associative online-softmax combine)
#pragma unroll
  for (int k = 0; k < PAIRS; ++k) accS[wv][k][lane] = accp[k];
  msS[wv][0][lane] = m_run;
  msS[wv][1][lane] = ssum;
  __syncthreads();
  if (win == 0 && valid) {
    const int wA = slot * 2, wB = slot * 2 + 1;
    const float mA = msS[wA][0][lane], mB = msS[wB][0][lane];
    const float ms = fmaxf(mA, mB);
    const float fA = (mA == -INFINITY) ? 0.f : __expf(mA - ms);
    const float fB = (mB == -INFINITY) ? 0.f : __expf(mB - ms);
    const float st = fA * msS[wA][1][lane] + fB * msS[wB][1][lane];
    const float inv = (end > beg) ? 1.f / st : 0.f;
    u32 ow[PAIRS];
#pragma unroll
    for (int k = 0; k < PAIRS; ++k) {
      f32x2 aA = accS[wA][k][lane], aB = accS[wB][k][lane];
      float a0 = fA * aA[0] + fB * aB[0];
      float a1 = fA * aA[1] + fB * aB[1];
      float o0 = a0 * inv + bias[j0 + 2 * k];
      float o1 = a1 * inv + bias[j0 + 2 * k + 1];
      o0 = o0 / (1.f + __expf(-o0));
      o1 = o1 / (1.f + __expf(-o1));
      hbf16 h0 = __float2bfloat16(o0), h1 = __float2bfloat16(o1);
      ow[k] = (u32)(*(unsigned short*)&h0) | ((u32)(*(unsigned short*)&h1) << 16);
    }
    *(uint2*)((u32*)((short*)out + (size_t)d * HC + j0)) = *(const uint2*)ow;
  }
}

// ---------------- fused GATv2 layer 2: TWO WAVES PER NODE (PAIRS=4, CPT=8) --------
__global__ __launch_bounds__(256) void fused_gat_w2_kernel(
    const hbf16* __restrict__ xl, const hbf16* __restrict__ xr, int ldx,
    const float* __restrict__ ea, const float* __restrict__ We,
    const float* __restrict__ att, const int* __restrict__ src,
    const int* __restrict__ Pend, const int* __restrict__ perm,
    const float* __restrict__ bias, hbf16* __restrict__ out,
    float* __restrict__ logit_out, float2* __restrict__ msbuf, int NN) {
  constexpr int PAIRS = 4, HC = 1024;
  const int lane = threadIdx.x & 63;
  const int wv = threadIdx.x >> 6;
  const int w = wv & 1;
  const int d = blockIdx.x * 2 + (wv >> 1);
  __shared__ float4 s_ef[4][64];
  if (d >= NN) return;
  const int beg = (d == 0) ? 0 : Pend[d - 1];
  const int end = Pend[d];
  const int hgrp = (w << 1) | (lane >> 5);
  const int j0 = hgrp * 256 + (lane & 31) * 8;

  f32x2 w0p[PAIRS], w1p[PAIRS], w2p[PAIRS], atp[PAIRS], xrp[PAIRS];
  {
    u32 xraw[PAIRS];
    *(uint4*)xraw = *(const uint4*)((const u32*)((const short*)xr + (size_t)d * ldx + j0));
#pragma unroll
    for (int k = 0; k < PAIRS; ++k) {
      xrp[k] = bf2pair(xraw[k]);
      w0p[k] = *(const f32x2*)(We + j0 + 2 * k);
      w1p[k] = *(const f32x2*)(We + HC + j0 + 2 * k);
      w2p[k] = *(const f32x2*)(We + 2 * HC + j0 + 2 * k);
      atp[k] = *(const f32x2*)(att + j0 + 2 * k);
    }
  }
  f32x2 p02;
  p02[0] = 0.2f; p02[1] = 0.2f;

  float m_run = -INFINITY, ssum = 0.f;
  f32x2 accp[PAIRS];
#pragma unroll
  for (int k = 0; k < PAIRS; ++k) accp[k] = {0.f, 0.f};

  const short* xls = (const short*)xl;

#define LOADR(R, IDX)                                                          \
  {                                                                            \
    int s_ = __builtin_amdgcn_readlane(sv, (IDX));                             \
    *(uint4*)(R) = *(const uint4*)((const u32*)(xls + (size_t)s_ * ldx + j0)); \
  }

#define DOT2(R, E01, E22, XV, POUT)                                            \
  {                                                                            \
    f32x2 q2 = {0.f, 0.f};                                                     \
    _Pragma("unroll") for (int k = 0; k < PAIRS; ++k) {                        \
      (XV)[k] = bf2pair((R)[k]);                                               \
      f32x2 u = pk_add((XV)[k], xrp[k]);                                       \
      u = pk_fma_b0(w0p[k], (E01), u);                                         \
      u = pk_fma_b1(w1p[k], (E01), u);                                         \
      u = pk_fma(w2p[k], (E22), u);                                            \
      f32x2 t = pk_mul(u, p02);                                                \
      f32x2 l;                                                                 \
      l[0] = fmaxf(u[0], t[0]);                                                \
      l[1] = fmaxf(u[1], t[1]);                                                \
      q2 = pk_fma(l, atp[k], q2);                                              \
    }                                                                          \
    (POUT) = q2[0] + q2[1];                                                    \
  }

#define SMUP2(P, XV, I)                                                        \
  {                                                                            \
    if ((lane & 31) == 0) {                                                    \
      const int eid_ = __builtin_amdgcn_readlane(eidv, (I));                   \
      logit_out[(size_t)eid_ * 4 + hgrp] = (P);                                \
    }                                                                          \
    if (__any((P) > m_run)) {                                                  \
      const float nm = fmaxf(m_run, (P));                                      \
      const float sc = __expf(m_run - nm);                                     \
      ssum *= sc;                                                              \
      f32x2 scp; scp[0] = sc; scp[1] = sc;                                     \
      _Pragma("unroll") for (int k = 0; k < PAIRS; ++k)                        \
          accp[k] = pk_mul_b0(accp[k], scp);                                   \
      m_run = nm;                                                              \
    }                                                                          \
    const float pe = __expf((P) - m_run);                                      \
    ssum += pe;                                                                \
    f32x2 pep; pep[0] = pe; pep[1] = pe;                                       \
    _Pragma("unroll") for (int k = 0; k < PAIRS; ++k)                          \
        accp[k] = pk_fma_b0((XV)[k], pep, accp[k]);                            \
  }

#define PROC2(RA, RB, IBASE)                                                   \
  {                                                                            \
    const int iA = (IBASE), iB = (IBASE) + 1;                                  \
    const float4 efA = s_ef[wv][iA];                                           \
    const float4 efB = s_ef[wv][iB];                                           \
    f32x2 eA01, eA22, eB01, eB22;                                              \
    eA01[0] = efA.x; eA01[1] = efA.y; eA22[0] = efA.z; eA22[1] = efA.w;        \
    eB01[0] = efB.x; eB01[1] = efB.y; eB22[0] = efB.z; eB22[1] = efB.w;        \
    f32x2 xvA[PAIRS], xvB[PAIRS];                                              \
    float pA, pB;                                                              \
    DOT2(RA, eA01, eA22, xvA, pA);                                             \
    DOT2(RB, eB01, eB22, xvB, pB);                                             \
    LOADR(RA, min(iA + 4, nbm1));                                              \
    LOADR(RB, min(iB + 4, nbm1));                                              \
    pA = dpp_add<0xB1>(pA);  pB = dpp_add<0xB1>(pB);                           \
    pA = dpp_add<0x4E>(pA);  pB = dpp_add<0x4E>(pB);                           \
    pA = dpp_add<0x141>(pA); pB = dpp_add<0x141>(pB);                          \
    pA = dpp_add<0x140>(pA); pB = dpp_add<0x140>(pB);                          \
    pA = swz_add16(pA);      pB = swz_add16(pB);                               \
    SMUP2(pA, xvA, iA);                                                        \
    SMUP2(pB, xvB, iB);                                                        \
  }

#define TAIL2(R, I)                                                            \
  {                                                                            \
    const float4 ef = s_ef[wv][I];                                             \
    f32x2 e01, e22;                                                            \
    e01[0] = ef.x; e01[1] = ef.y; e22[0] = ef.z; e22[1] = ef.w;                \
    f32x2 xv[PAIRS];                                                           \
    float p;                                                                   \
    DOT2(R, e01, e22, xv, p);                                                  \
    p = dpp_add<0xB1>(p);                                                      \
    p = dpp_add<0x4E>(p);                                                      \
    p = dpp_add<0x141>(p);                                                     \
    p = dpp_add<0x140>(p);                                                     \
    p = swz_add16(p);                                                          \
    SMUP2(p, xv, I);                                                           \
  }

  for (int base = beg; base < end; base += 64) {
    const int nb = min(64, end - base);
    const int nbm1 = nb - 1;
    const int nb4 = nb & ~3;
    int eidv = 0, sv = 0;
    if (lane < nb) {
      eidv = perm[base + lane];
      sv = src[eidv];
      float a0 = ea[3 * (size_t)eidv], a1 = ea[3 * (size_t)eidv + 1],
            a2 = ea[3 * (size_t)eidv + 2];
      s_ef[wv][lane] = make_float4(a0, a1, a2, a2);
    }
    asm volatile("s_waitcnt lgkmcnt(0)" ::: "memory");

    u32 r0[PAIRS], r1[PAIRS], r2[PAIRS], r3[PAIRS];
    LOADR(r0, 0);
    LOADR(r1, min(1, nbm1));
    LOADR(r2, min(2, nbm1));
    LOADR(r3, min(3, nbm1));

    for (int i = 0; i < nb4; i += 4) {
      PROC2(r0, r1, i);
      PROC2(r2, r3, i + 2);
    }
    if (nb4 + 0 < nb) TAIL2(r0, nb4 + 0);
    if (nb4 + 1 < nb) TAIL2(r1, nb4 + 1);
    if (nb4 + 2 < nb) TAIL2(r2, nb4 + 2);
  }
#undef LOADR
#undef DOT2
#undef SMUP2
#undef PROC2
#undef TAIL2

  const float inv = (end > beg) ? 1.f / ssum : 0.f;
  u32 ow[PAIRS];
#pragma unroll
  for (int k = 0; k < PAIRS; ++k) {
    float o0 = accp[k][0] * inv + bias[j0 + 2 * k];
    float o1 = accp[k][1] * inv + bias[j0 + 2 * k + 1];
    hbf16 h0 = __float2bfloat16(o0), h1 = __float2bfloat16(o1);
    ow[k] = (u32)(*(unsigned short*)&h0) | ((u32)(*(unsigned short*)&h1) << 16);
  }
  *(uint4*)((u32*)((short*)out + (size_t)d * HC + j0)) = *(const uint4*)ow;
  if ((lane & 31) == 0) msbuf[d * 4 + hgrp] = make_float2(m_run, ssum);
}

extern "C" void kernel_launch(void* const* d_in, const int* in_sizes, int n_in,
                              void* d_out, int out_size, void* d_ws, size_t ws_size,
                              hipStream_t stream) {
  const float* x    = (const float*)d_in[0];
  const int*   ei   = (const int*)d_in[1];
  const float* ea   = (const float*)d_in[2];
  const float* W1l  = (const float*)d_in[3];
  const float* b1l  = (const float*)d_in[4];
  const float* W1r  = (const float*)d_in[5];
  const float* b1r  = (const float*)d_in[6];
  const float* W1e  = (const float*)d_in[7];
  const float* att1 = (const float*)d_in[8];
  const float* bias1= (const float*)d_in[9];
  const float* W2l  = (const float*)d_in[10];
  const float* b2l  = (const float*)d_in[11];
  const float* W2r  = (const float*)d_in[12];
  const float* b2r  = (const float*)d_in[13];
  const float* W2e  = (const float*)d_in[14];
  const float* att2 = (const float*)d_in[15];
  const float* bias2= (const float*)d_in[16];
  const float* Wp   = (const float*)d_in[17];
  const float* bp   = (const float*)d_in[18];

  const int N = in_sizes[0] / 256;  // 10000
  const int E = in_sizes[1] / 2;    // 320000
  const int* srcI = ei;
  const int* dstI = ei + E;

  // workspace (~68 MB)
  float* wsf = (float*)d_ws;
  float2* msbuf = (float2*)wsf;                   // 4N float2
  int*   P    = (int*)(wsf + (size_t)8 * N);      // N
  int*   part = P + N;                            // 256 (scan partials)
  int*   perm = part + 256;                       // E
  hbf16* xb   = (hbf16*)(perm + E);               // N*256 (x bf16)
  hbf16* xlr  = xb + (size_t)N * 256;             // N*2048 (merged xl|xr; L1 uses N*512)
  hbf16* ho   = xlr + (size_t)N * 2048;           // N*1024 (h first N*256, then out2)
  hbf16* W1lt = ho + (size_t)N * 1024;            // 256*256  (W1rt adjacent)
  hbf16* W1rt = W1lt + 256 * 256;
  hbf16* W2lt = W1rt + 256 * 256;                 // 1024*256 (W2rt adjacent)
  hbf16* W2rt = W2lt + 1024 * 256;
  hbf16* Wpt  = W2rt + 1024 * 256;                // 256*1024

  float* yout = (float*)d_out;                    // N*256
  float* alpha_out = yout + (size_t)N * 256;      // E*4

  const int eB = (E + 255) / 256;                 // 1250
  const int sB = (N + 255) / 256;                 // 40 scan blocks
  const int gy = (N + 127) / 128;                 // 79 GEMM row-blocks

  // 1. memset P
  hipMemsetAsync(P, 0, (size_t)N * 4, stream);

  // 2. hist + cvt(x) + weight transposes (one launch)
  const int nx = N * 256;
  const int nxB = (nx / 4 + 255) / 256;
  prep_hist_kernel<<<eB + nxB + 896, 256, 0, stream>>>(
      dstI, P, E, eB, x, xb, nx, nxB, W1l, W1lt, W1r, W1rt, W2l, W2lt, W2r, W2rt,
      Wp, Wpt);

  // 3-4. CSR scan (2 launches)
  scan_sum_kernel<<<sB, 256, 0, stream>>>(P, part, N);
  scan_apply_kernel<<<sB, 256, 0, stream>>>(P, part, N, sB);

  // 5. scatter + GEMM1 (merged; deps: scan_apply for scatter, prep for GEMM)
  scatter_gemm1_kernel<<<eB + 4 * gy, 256, 0, stream>>>(
      dstI, P, perm, E, eB, xb, W1lt, b1l, b1r, xlr, N);

  // 6. fused layer 1 (2 waves/node)
  fused_gat_l1_kernel<<<(N + 1) / 2, 256, 0, stream>>>(
      xlr, xlr + 256, 512, ea, W1e, att1, srcI, P, perm, bias1, ho /*h*/, N);

  // 7. GEMM2 (merged l|r, N=2048)
  mfma_gemm_kernel<hbf16><<<dim3(16, gy), 256, 0, stream>>>(
      ho, W2lt, b2l, b2r, 1024, xlr, N, 2048, 256);

  // 8. fused layer 2
  fused_gat_w2_kernel<<<(N + 1) / 2, 256, 0, stream>>>(
      xlr, xlr + 1024, 2048, ea, W2e, att2, srcI, P, perm, bias2, ho /*out2*/,
      alpha_out, msbuf, N);

  // 9. alpha + projector GEMM (merged; both depend only on fused2)
  alpha_gemmp_kernel<<<2 * gy + (E * 4 + 255) / 256, 256, 0, stream>>>(
      alpha_out, msbuf, dstI, E * 4, 2 * gy, ho, Wpt, bp, yout, N);
}

// Round 17
// 310.957 us; speedup vs baseline: 1.0238x; 1.0238x over previous
//
#include <hip/hip_runtime.h>
#include <hip/hip_bf16.h>

typedef __hip_bfloat16 hbf16;
typedef unsigned int u32;
typedef __attribute__((ext_vector_type(2))) float f32x2;
typedef __attribute__((ext_vector_type(8))) short bf16x8;
typedef __attribute__((ext_vector_type(4))) float f32x4;

__device__ __forceinline__ f32x2 bf2pair(u32 v) {
  f32x2 o;
  o[0] = __uint_as_float(v << 16);
  o[1] = __uint_as_float(v & 0xffff0000u);
  return o;
}

// ---- packed f32 VOP3P helpers (NOTE: no v_pk_max_f32 on gfx950!) ----
__device__ __forceinline__ f32x2 pk_add(f32x2 a, f32x2 b) {
  f32x2 d; asm("v_pk_add_f32 %0, %1, %2" : "=v"(d) : "v"(a), "v"(b)); return d;
}
__device__ __forceinline__ f32x2 pk_mul(f32x2 a, f32x2 b) {
  f32x2 d; asm("v_pk_mul_f32 %0, %1, %2" : "=v"(d) : "v"(a), "v"(b)); return d;
}
__device__ __forceinline__ f32x2 pk_fma(f32x2 a, f32x2 b, f32x2 c) {
  f32x2 d; asm("v_pk_fma_f32 %0, %1, %2, %3" : "=v"(d) : "v"(a), "v"(b), "v"(c)); return d;
}
__device__ __forceinline__ f32x2 pk_fma_b0(f32x2 a, f32x2 b, f32x2 c) {
  f32x2 d;
  asm("v_pk_fma_f32 %0, %1, %2, %3 op_sel:[0,0,0] op_sel_hi:[1,0,1]"
      : "=v"(d) : "v"(a), "v"(b), "v"(c));
  return d;
}
__device__ __forceinline__ f32x2 pk_fma_b1(f32x2 a, f32x2 b, f32x2 c) {
  f32x2 d;
  asm("v_pk_fma_f32 %0, %1, %2, %3 op_sel:[0,1,0] op_sel_hi:[1,1,1]"
      : "=v"(d) : "v"(a), "v"(b), "v"(c));
  return d;
}
__device__ __forceinline__ f32x2 pk_mul_b0(f32x2 a, f32x2 b) {
  f32x2 d;
  asm("v_pk_mul_f32 %0, %1, %2 op_sel:[0,0] op_sel_hi:[1,0]"
      : "=v"(d) : "v"(a), "v"(b));
  return d;
}

// ---- DPP butterfly add steps (pure VALU, no DS) ----
template <int CTRL>
__device__ __forceinline__ float dpp_add(float p) {
  int t = __builtin_amdgcn_update_dpp(0, __float_as_int(p), CTRL, 0xF, 0xF, true);
  return p + __int_as_float(t);
}
// xor16 within 32-lane group via ds_swizzle bit-mode (no addr calc)
__device__ __forceinline__ float swz_add16(float p) {
  int t = __builtin_amdgcn_ds_swizzle(__float_as_int(p), 0x401F);
  return p + __int_as_float(t);
}

__device__ __forceinline__ void storeO(float* p, float v) { *p = v; }
__device__ __forceinline__ void storeO(hbf16* p, float v) { *p = __float2bfloat16(v); }

// ---------------- prep: hist + cvt(x) + 5 weight transposes, one launch ----------
__device__ __forceinline__ void tcvt_dev(const float* __restrict__ W,
                                         hbf16* __restrict__ Wt, int K, int N,
                                         int b, int tid, hbf16 (*tile)[33]) {
  const int nb32 = N >> 5;
  const int n0 = (b % nb32) << 5, k0 = (b / nb32) << 5;
  const int tx = tid & 31, ty = tid >> 5;
#pragma unroll
  for (int i = 0; i < 4; ++i)
    tile[ty * 4 + i][tx] = __float2bfloat16(W[(size_t)(k0 + ty * 4 + i) * N + n0 + tx]);
  __syncthreads();
#pragma unroll
  for (int i = 0; i < 4; ++i)
    Wt[(size_t)(n0 + ty * 4 + i) * K + k0 + tx] = tile[tx][ty * 4 + i];
}

__global__ __launch_bounds__(256) void prep_hist_kernel(
    const int* __restrict__ dst, int* __restrict__ P, int E, int eB,
    const float* __restrict__ x, hbf16* __restrict__ xb, int n, int nxB,
    const float* __restrict__ W1l, hbf16* __restrict__ W1lt,
    const float* __restrict__ W1r, hbf16* __restrict__ W1rt,
    const float* __restrict__ W2l, hbf16* __restrict__ W2lt,
    const float* __restrict__ W2r, hbf16* __restrict__ W2rt,
    const float* __restrict__ Wp, hbf16* __restrict__ Wpt) {
  __shared__ hbf16 tile[32][33];
  int b = blockIdx.x;
  const int tid = threadIdx.x;
  if (b < eB) {
    int i = b * 256 + tid;
    if (i < E) atomicAdd(&P[dst[i]], 1);
    return;
  }
  b -= eB;
  if (b < nxB) {
    int i = (b * 256 + tid) * 4;
    if (i < n) {
      float4 v = *(const float4*)(x + i);
      xb[i] = __float2bfloat16(v.x);
      xb[i + 1] = __float2bfloat16(v.y);
      xb[i + 2] = __float2bfloat16(v.z);
      xb[i + 3] = __float2bfloat16(v.w);
    }
    return;
  }
  b -= nxB;
  if (b < 64) { tcvt_dev(W1l, W1lt, 256, 256, b, tid, tile); return; }
  b -= 64;
  if (b < 64) { tcvt_dev(W1r, W1rt, 256, 256, b, tid, tile); return; }
  b -= 64;
  if (b < 256) { tcvt_dev(W2l, W2lt, 256, 1024, b, tid, tile); return; }
  b -= 256;
  if (b < 256) { tcvt_dev(W2r, W2rt, 256, 1024, b, tid, tile); return; }
  b -= 256;
  tcvt_dev(Wp, Wpt, 1024, 256, b, tid, tile);
}

// ---- MFMA GEMM body (device): C[M,N] = A@Bt^T + dual bias, reg-dbuf k-pipeline ----
template <typename OutT>
__device__ __forceinline__ void gemm_body(
    int bx, int by, const hbf16* __restrict__ A, const hbf16* __restrict__ Bt,
    const float* __restrict__ bias0, const float* __restrict__ bias1, int NS,
    OutT* __restrict__ C, int M, int N, int K) {
  const int tid = threadIdx.x, lane = tid & 63, w = tid >> 6;
  const int wr = w >> 1, wc = w & 1;
  const int rowb = by * 128 + wr * 64;
  const int colb = bx * 128 + wc * 64;
  const int lr = lane & 15, lk = (lane >> 4) * 8;

  f32x4 acc[4][4];
#pragma unroll
  for (int mi = 0; mi < 4; ++mi)
#pragma unroll
    for (int ni = 0; ni < 4; ++ni) acc[mi][ni] = {0.f, 0.f, 0.f, 0.f};

  const short* Ap = (const short*)A;
  const short* Bp = (const short*)Bt;

  int ar[4];
#pragma unroll
  for (int mi = 0; mi < 4; ++mi) {
    int r = rowb + mi * 16 + lr;
    ar[mi] = (r < M) ? r : (M - 1);  // clamp: garbage rows never stored
  }

  bf16x8 afC[4], bfC[4];
#pragma unroll
  for (int mi = 0; mi < 4; ++mi)
    afC[mi] = *(const bf16x8*)(Ap + (size_t)ar[mi] * K + lk);
#pragma unroll
  for (int ni = 0; ni < 4; ++ni)
    bfC[ni] = *(const bf16x8*)(Bp + (size_t)(colb + ni * 16 + lr) * K + lk);

  for (int k0 = 0; k0 < K; k0 += 32) {
    bf16x8 afN[4], bfN[4];
    const int kn = k0 + 32;
    if (kn < K) {
#pragma unroll
      for (int mi = 0; mi < 4; ++mi)
        afN[mi] = *(const bf16x8*)(Ap + (size_t)ar[mi] * K + kn + lk);
#pragma unroll
      for (int ni = 0; ni < 4; ++ni)
        bfN[ni] = *(const bf16x8*)(Bp + (size_t)(colb + ni * 16 + lr) * K + kn + lk);
    }
#pragma unroll
    for (int mi = 0; mi < 4; ++mi)
#pragma unroll
      for (int ni = 0; ni < 4; ++ni)
        acc[mi][ni] = __builtin_amdgcn_mfma_f32_16x16x32_bf16(afC[mi], bfC[ni],
                                                              acc[mi][ni], 0, 0, 0);
#pragma unroll
    for (int mi = 0; mi < 4; ++mi) afC[mi] = afN[mi];
#pragma unroll
    for (int ni = 0; ni < 4; ++ni) bfC[ni] = bfN[ni];
  }

  float bv[4];
#pragma unroll
  for (int ni = 0; ni < 4; ++ni) {
    int gc = colb + ni * 16 + lr;
    bv[ni] = (gc < NS) ? bias0[gc] : bias1[gc - NS];
  }
#pragma unroll
  for (int mi = 0; mi < 4; ++mi) {
    const int row0 = rowb + mi * 16 + (lane >> 4) * 4;
#pragma unroll
    for (int r = 0; r < 4; ++r) {
      const int row = row0 + r;
      if (row >= M) continue;
#pragma unroll
      for (int ni = 0; ni < 4; ++ni)
        storeO(&C[(size_t)row * N + colb + ni * 16 + lr], acc[mi][ni][r] + bv[ni]);
    }
  }
}

template <typename OutT>
__global__ __launch_bounds__(256) void mfma_gemm_kernel(
    const hbf16* __restrict__ A, const hbf16* __restrict__ Bt,
    const float* __restrict__ bias0, const float* __restrict__ bias1, int NS,
    OutT* __restrict__ C, int M, int N, int K) {
  gemm_body<OutT>(blockIdx.x, blockIdx.y, A, Bt, bias0, bias1, NS, C, M, N, K);
}

// ---------------- CSR scan (2 launches) ----------------
__global__ __launch_bounds__(256) void scan_sum_kernel(const int* __restrict__ P,
                                                       int* __restrict__ part, int n) {
  __shared__ int s[256];
  int i = blockIdx.x * 256 + threadIdx.x;
  s[threadIdx.x] = (i < n) ? P[i] : 0;
  __syncthreads();
#pragma unroll
  for (int off = 128; off; off >>= 1) {
    if (threadIdx.x < off) s[threadIdx.x] += s[threadIdx.x + off];
    __syncthreads();
  }
  if (threadIdx.x == 0) part[blockIdx.x] = s[0];
}

// each block redundantly scans the (<=256) raw partials, then scans its chunk
__global__ __launch_bounds__(256) void scan_apply_kernel(int* __restrict__ P,
                                                         const int* __restrict__ part,
                                                         int n, int nb) {
  __shared__ int sp[256];
  __shared__ int s[256];
  int pv = (threadIdx.x < nb) ? part[threadIdx.x] : 0;
  sp[threadIdx.x] = pv;
  __syncthreads();
#pragma unroll
  for (int off = 1; off < 256; off <<= 1) {
    int t = (threadIdx.x >= off) ? sp[threadIdx.x - off] : 0;
    __syncthreads();
    sp[threadIdx.x] += t;
    __syncthreads();
  }
  const int boff = (blockIdx.x == 0) ? 0 : sp[blockIdx.x - 1];
  int i = blockIdx.x * 256 + threadIdx.x;
  int v = (i < n) ? P[i] : 0;
  s[threadIdx.x] = v;
  __syncthreads();
#pragma unroll
  for (int off = 1; off < 256; off <<= 1) {
    int t = (threadIdx.x >= off) ? s[threadIdx.x - off] : 0;
    __syncthreads();
    s[threadIdx.x] += t;
    __syncthreads();
  }
  if (i < n) P[i] = s[threadIdx.x] - v + boff;
}

// ---------------- scatter + GEMM1 merged ----------------
__global__ __launch_bounds__(256) void scatter_gemm1_kernel(
    const int* __restrict__ dst, int* __restrict__ P, int* __restrict__ perm,
    int E, int eB,
    const hbf16* __restrict__ A, const hbf16* __restrict__ Bt,
    const float* __restrict__ bias0, const float* __restrict__ bias1,
    hbf16* __restrict__ C, int M) {
  if ((int)blockIdx.x < eB) {
    int i = blockIdx.x * 256 + threadIdx.x;
    if (i < E) {
      int pos = atomicAdd(&P[dst[i]], 1);
      perm[pos] = i;
    }
    return;
  }
  const int b = blockIdx.x - eB;
  gemm_body<hbf16>(b & 3, b >> 2, A, Bt, bias0, bias1, 256, C, M, 512, 256);
}

// ---------------- alpha + projector GEMM merged ----------------
__global__ __launch_bounds__(256) void alpha_gemmp_kernel(
    float* __restrict__ la, const float2* __restrict__ msbuf,
    const int* __restrict__ dst, int n4, int gp,
    const hbf16* __restrict__ A, const hbf16* __restrict__ Bt,
    const float* __restrict__ bias, float* __restrict__ C, int M) {
  if ((int)blockIdx.x < gp) {
    gemm_body<float>(blockIdx.x & 1, blockIdx.x >> 1, A, Bt, bias, bias, 256, C,
                     M, 256, 1024);
    return;
  }
  int i = (blockIdx.x - gp) * 256 + threadIdx.x;
  if (i >= n4) return;
  int e = i >> 2, h = i & 3;
  int d = dst[e];
  float2 ms = msbuf[d * 4 + h];
  la[i] = __expf(la[i] - ms.x) / ms.y;
}

// ---------------- fused GATv2 layer 1: ONE WAVE PER NODE (PAIRS=2, CPT=4) --------
// bulk: static ring names (NO runtime pointer select — scratch-spill hazard),
// clamped branchless prefetch; explicit <=3-edge tail on r0/r1/r2.
__global__ __launch_bounds__(256) void fused_gat_l1_kernel(
    const hbf16* __restrict__ xl, const hbf16* __restrict__ xr, int ldx,
    const float* __restrict__ ea, const float* __restrict__ We,
    const float* __restrict__ att, const int* __restrict__ src,
    const int* __restrict__ Pend, const int* __restrict__ perm,
    const float* __restrict__ bias, hbf16* __restrict__ out, int NN) {
  constexpr int PAIRS = 2, HC = 256;
  const int lane = threadIdx.x & 63;
  const int w = threadIdx.x >> 6;
  const int d = blockIdx.x * 4 + w;
  __shared__ float4 s_ef[4][64];
  if (d >= NN) return;
  const int beg = (d == 0) ? 0 : Pend[d - 1];
  const int end = Pend[d];
  const int j0 = lane * 4;

  f32x2 w0p[PAIRS], w1p[PAIRS], w2p[PAIRS], atp[PAIRS], xrp[PAIRS];
  {
    u32 xraw[PAIRS];
    *(uint2*)xraw = *(const uint2*)((const u32*)((const short*)xr + (size_t)d * ldx + j0));
#pragma unroll
    for (int k = 0; k < PAIRS; ++k) {
      xrp[k] = bf2pair(xraw[k]);
      w0p[k] = *(const f32x2*)(We + j0 + 2 * k);
      w1p[k] = *(const f32x2*)(We + HC + j0 + 2 * k);
      w2p[k] = *(const f32x2*)(We + 2 * HC + j0 + 2 * k);
      atp[k] = *(const f32x2*)(att + j0 + 2 * k);
    }
  }
  f32x2 p02;
  p02[0] = 0.2f; p02[1] = 0.2f;

  float m_run = -INFINITY, ssum = 0.f;
  f32x2 accp[PAIRS];
#pragma unroll
  for (int k = 0; k < PAIRS; ++k) accp[k] = {0.f, 0.f};

  const short* xls = (const short*)xl;

#define LOADR1(R, IDX)                                                          \
  {                                                                             \
    int s_ = __builtin_amdgcn_readlane(sv, (IDX));                              \
    *(uint2*)(R) = *(const uint2*)((const u32*)(xls + (size_t)s_ * ldx + j0));  \
  }

#define DOT1(R, E01, E22, XV, POUT)                                            \
  {                                                                            \
    f32x2 q2 = {0.f, 0.f};                                                     \
    _Pragma("unroll") for (int k = 0; k < PAIRS; ++k) {                        \
      (XV)[k] = bf2pair((R)[k]);                                               \
      f32x2 u = pk_add((XV)[k], xrp[k]);                                       \
      u = pk_fma_b0(w0p[k], (E01), u);                                         \
      u = pk_fma_b1(w1p[k], (E01), u);                                         \
      u = pk_fma(w2p[k], (E22), u);                                            \
      f32x2 t = pk_mul(u, p02);                                                \
      f32x2 l;                                                                 \
      l[0] = fmaxf(u[0], t[0]);                                                \
      l[1] = fmaxf(u[1], t[1]);                                                \
      q2 = pk_fma(l, atp[k], q2);                                              \
    }                                                                          \
    (POUT) = q2[0] + q2[1];                                                    \
  }

#define SMUP1(P, XV)                                                           \
  {                                                                            \
    if (__any((P) > m_run)) {                                                  \
      const float nm = fmaxf(m_run, (P));                                      \
      const float sc = __expf(m_run - nm);                                     \
      ssum *= sc;                                                              \
      f32x2 scp; scp[0] = sc; scp[1] = sc;                                     \
      _Pragma("unroll") for (int k = 0; k < PAIRS; ++k)                        \
          accp[k] = pk_mul_b0(accp[k], scp);                                   \
      m_run = nm;                                                              \
    }                                                                          \
    const float pe = __expf((P) - m_run);                                      \
    ssum += pe;                                                                \
    f32x2 pep; pep[0] = pe; pep[1] = pe;                                       \
    _Pragma("unroll") for (int k = 0; k < PAIRS; ++k)                          \
        accp[k] = pk_fma_b0((XV)[k], pep, accp[k]);                            \
  }

// bulk pair: RA/RB are STATIC names (r0..r3), clamped prefetch
#define PROC1(RA, RB, IBASE)                                                   \
  {                                                                            \
    const int iA = (IBASE), iB = (IBASE) + 1;                                  \
    const float4 efA = s_ef[w][iA];                                            \
    const float4 efB = s_ef[w][iB];                                            \
    f32x2 eA01, eA22, eB01, eB22;                                              \
    eA01[0] = efA.x; eA01[1] = efA.y; eA22[0] = efA.z; eA22[1] = efA.w;        \
    eB01[0] = efB.x; eB01[1] = efB.y; eB22[0] = efB.z; eB22[1] = efB.w;        \
    f32x2 xvA[PAIRS], xvB[PAIRS];                                              \
    float pA, pB;                                                              \
    DOT1(RA, eA01, eA22, xvA, pA);                                             \
    DOT1(RB, eB01, eB22, xvB, pB);                                             \
    LOADR1(RA, min(iA + 4, nbm1));                                             \
    LOADR1(RB, min(iB + 4, nbm1));                                             \
    pA = dpp_add<0xB1>(pA);  pB = dpp_add<0xB1>(pB);                           \
    pA = dpp_add<0x4E>(pA);  pB = dpp_add<0x4E>(pB);                           \
    pA = dpp_add<0x141>(pA); pB = dpp_add<0x141>(pB);                          \
    pA = dpp_add<0x140>(pA); pB = dpp_add<0x140>(pB);                          \
    SMUP1(pA, xvA);                                                            \
    SMUP1(pB, xvB);                                                            \
  }

#define TAIL1(R, I)                                                            \
  {                                                                            \
    const float4 ef = s_ef[w][I];                                              \
    f32x2 e01, e22;                                                            \
    e01[0] = ef.x; e01[1] = ef.y; e22[0] = ef.z; e22[1] = ef.w;                \
    f32x2 xv[PAIRS];                                                           \
    float p;                                                                   \
    DOT1(R, e01, e22, xv, p);                                                  \
    p = dpp_add<0xB1>(p);                                                      \
    p = dpp_add<0x4E>(p);                                                      \
    p = dpp_add<0x141>(p);                                                     \
    p = dpp_add<0x140>(p);                                                     \
    SMUP1(p, xv);                                                              \
  }

  for (int base = beg; base < end; base += 64) {
    const int nb = min(64, end - base);
    const int nbm1 = nb - 1;
    const int nb4 = nb & ~3;
    int sv = 0;
    if (lane < nb) {
      int eid = perm[base + lane];
      sv = src[eid];
      float a0 = ea[3 * (size_t)eid], a1 = ea[3 * (size_t)eid + 1],
            a2 = ea[3 * (size_t)eid + 2];
      s_ef[w][lane] = make_float4(a0, a1, a2, a2);
    }
    asm volatile("s_waitcnt lgkmcnt(0)" ::: "memory");

    u32 r0[PAIRS], r1[PAIRS], r2[PAIRS], r3[PAIRS];
    LOADR1(r0, 0);
    LOADR1(r1, min(1, nbm1));
    LOADR1(r2, min(2, nbm1));
    LOADR1(r3, min(3, nbm1));

    for (int i = 0; i < nb4; i += 4) {
      PROC1(r0, r1, i);
      PROC1(r2, r3, i + 2);
    }
    // tail (<=3 edges): ring reg t holds edge nb4+t
    if (nb4 + 0 < nb) TAIL1(r0, nb4 + 0);
    if (nb4 + 1 < nb) TAIL1(r1, nb4 + 1);
    if (nb4 + 2 < nb) TAIL1(r2, nb4 + 2);
  }
#undef LOADR1
#undef DOT1
#undef SMUP1
#undef PROC1
#undef TAIL1

  const float inv = (end > beg) ? 1.f / ssum : 0.f;
  u32 ow[PAIRS];
#pragma unroll
  for (int k = 0; k < PAIRS; ++k) {
    float o0 = accp[k][0] * inv + bias[j0 + 2 * k];
    float o1 = accp[k][1] * inv + bias[j0 + 2 * k + 1];
    o0 = o0 / (1.f + __expf(-o0));
    o1 = o1 / (1.f + __expf(-o1));
    hbf16 h0 = __float2bfloat16(o0), h1 = __float2bfloat16(o1);
    ow[k] = (u32)(*(unsigned short*)&h0) | ((u32)(*(unsigned short*)&h1) << 16);
  }
  *(uint2*)((u32*)((short*)out + (size_t)d * HC + j0)) = *(const uint2*)ow;
}

// ---------------- fused GATv2 layer 2: TWO WAVES PER NODE (PAIRS=4, CPT=8) --------
__global__ __launch_bounds__(256) void fused_gat_w2_kernel(
    const hbf16* __restrict__ xl, const hbf16* __restrict__ xr, int ldx,
    const float* __restrict__ ea, const float* __restrict__ We,
    const float* __restrict__ att, const int* __restrict__ src,
    const int* __restrict__ Pend, const int* __restrict__ perm,
    const float* __restrict__ bias, hbf16* __restrict__ out,
    float* __restrict__ logit_out, float2* __restrict__ msbuf, int NN) {
  constexpr int PAIRS = 4, HC = 1024;
  const int lane = threadIdx.x & 63;
  const int wv = threadIdx.x >> 6;
  const int w = wv & 1;
  const int d = blockIdx.x * 2 + (wv >> 1);
  __shared__ float4 s_ef[4][64];
  if (d >= NN) return;
  const int beg = (d == 0) ? 0 : Pend[d - 1];
  const int end = Pend[d];
  const int hgrp = (w << 1) | (lane >> 5);
  const int j0 = hgrp * 256 + (lane & 31) * 8;

  f32x2 w0p[PAIRS], w1p[PAIRS], w2p[PAIRS], atp[PAIRS], xrp[PAIRS];
  {
    u32 xraw[PAIRS];
    *(uint4*)xraw = *(const uint4*)((const u32*)((const short*)xr + (size_t)d * ldx + j0));
#pragma unroll
    for (int k = 0; k < PAIRS; ++k) {
      xrp[k] = bf2pair(xraw[k]);
      w0p[k] = *(const f32x2*)(We + j0 + 2 * k);
      w1p[k] = *(const f32x2*)(We + HC + j0 + 2 * k);
      w2p[k] = *(const f32x2*)(We + 2 * HC + j0 + 2 * k);
      atp[k] = *(const f32x2*)(att + j0 + 2 * k);
    }
  }
  f32x2 p02;
  p02[0] = 0.2f; p02[1] = 0.2f;

  float m_run = -INFINITY, ssum = 0.f;
  f32x2 accp[PAIRS];
#pragma unroll
  for (int k = 0; k < PAIRS; ++k) accp[k] = {0.f, 0.f};

  const short* xls = (const short*)xl;

#define LOADR(R, IDX)                                                          \
  {                                                                            \
    int s_ = __builtin_amdgcn_readlane(sv, (IDX));                             \
    *(uint4*)(R) = *(const uint4*)((const u32*)(xls + (size_t)s_ * ldx + j0)); \
  }

#define DOT2(R, E01, E22, XV, POUT)                                            \
  {                                                                            \
    f32x2 q2 = {0.f, 0.f};                                                     \
    _Pragma("unroll") for (int k = 0; k < PAIRS; ++k) {                        \
      (XV)[k] = bf2pair((R)[k]);                                               \
      f32x2 u = pk_add((XV)[k], xrp[k]);                                       \
      u = pk_fma_b0(w0p[k], (E01), u);                                         \
      u = pk_fma_b1(w1p[k], (E01), u);                                         \
      u = pk_fma(w2p[k], (E22), u);                                            \
      f32x2 t = pk_mul(u, p02);                                                \
      f32x2 l;                                                                 \
      l[0] = fmaxf(u[0], t[0]);                                                \
      l[1] = fmaxf(u[1], t[1]);                                                \
      q2 = pk_fma(l, atp[k], q2);                                              \
    }                                                                          \
    (POUT) = q2[0] + q2[1];                                                    \
  }

#define SMUP2(P, XV, I)                                                        \
  {                                                                            \
    if ((lane & 31) == 0) {                                                    \
      const int eid_ = __builtin_amdgcn_readlane(eidv, (I));                   \
      logit_out[(size_t)eid_ * 4 + hgrp] = (P);                                \
    }                                                                          \
    if (__any((P) > m_run)) {                                                  \
      const float nm = fmaxf(m_run, (P));                                      \
      const float sc = __expf(m_run - nm);                                     \
      ssum *= sc;                                                              \
      f32x2 scp; scp[0] = sc; scp[1] = sc;                                     \
      _Pragma("unroll") for (int k = 0; k < PAIRS; ++k)                        \
          accp[k] = pk_mul_b0(accp[k], scp);                                   \
      m_run = nm;                                                              \
    }                                                                          \
    const float pe = __expf((P) - m_run);                                      \
    ssum += pe;                                                                \
    f32x2 pep; pep[0] = pe; pep[1] = pe;                                       \
    _Pragma("unroll") for (int k = 0; k < PAIRS; ++k)                          \
        accp[k] = pk_fma_b0((XV)[k], pep, accp[k]);                            \
  }

#define PROC2(RA, RB, IBASE)                                                   \
  {                                                                            \
    const int iA = (IBASE), iB = (IBASE) + 1;                                  \
    const float4 efA = s_ef[wv][iA];                                           \
    const float4 efB = s_ef[wv][iB];                                           \
    f32x2 eA01, eA22, eB01, eB22;                                              \
    eA01[0] = efA.x; eA01[1] = efA.y; eA22[0] = efA.z; eA22[1] = efA.w;        \
    eB01[0] = efB.x; eB01[1] = efB.y; eB22[0] = efB.z; eB22[1] = efB.w;        \
    f32x2 xvA[PAIRS], xvB[PAIRS];                                              \
    float pA, pB;                                                              \
    DOT2(RA, eA01, eA22, xvA, pA);                                             \
    DOT2(RB, eB01, eB22, xvB, pB);                                             \
    LOADR(RA, min(iA + 4, nbm1));                                              \
    LOADR(RB, min(iB + 4, nbm1));                                              \
    pA = dpp_add<0xB1>(pA);  pB = dpp_add<0xB1>(pB);                           \
    pA = dpp_add<0x4E>(pA);  pB = dpp_add<0x4E>(pB);                           \
    pA = dpp_add<0x141>(pA); pB = dpp_add<0x141>(pB);                          \
    pA = dpp_add<0x140>(pA); pB = dpp_add<0x140>(pB);                          \
    pA = swz_add16(pA);      pB = swz_add16(pB);                               \
    SMUP2(pA, xvA, iA);                                                        \
    SMUP2(pB, xvB, iB);                                                        \
  }

#define TAIL2(R, I)                                                            \
  {                                                                            \
    const float4 ef = s_ef[wv][I];                                             \
    f32x2 e01, e22;                                                            \
    e01[0] = ef.x; e01[1] = ef.y; e22[0] = ef.z; e22[1] = ef.w;                \
    f32x2 xv[PAIRS];                                                           \
    float p;                                                                   \
    DOT2(R, e01, e22, xv, p);                                                  \
    p = dpp_add<0xB1>(p);                                                      \
    p = dpp_add<0x4E>(p);                                                      \
    p = dpp_add<0x141>(p);                                                     \
    p = dpp_add<0x140>(p);                                                     \
    p = swz_add16(p);                                                          \
    SMUP2(p, xv, I);                                                           \
  }

  for (int base = beg; base < end; base += 64) {
    const int nb = min(64, end - base);
    const int nbm1 = nb - 1;
    const int nb4 = nb & ~3;
    int eidv = 0, sv = 0;
    if (lane < nb) {
      eidv = perm[base + lane];
      sv = src[eidv];
      float a0 = ea[3 * (size_t)eidv], a1 = ea[3 * (size_t)eidv + 1],
            a2 = ea[3 * (size_t)eidv + 2];
      s_ef[wv][lane] = make_float4(a0, a1, a2, a2);
    }
    asm volatile("s_waitcnt lgkmcnt(0)" ::: "memory");

    u32 r0[PAIRS], r1[PAIRS], r2[PAIRS], r3[PAIRS];
    LOADR(r0, 0);
    LOADR(r1, min(1, nbm1));
    LOADR(r2, min(2, nbm1));
    LOADR(r3, min(3, nbm1));

    for (int i = 0; i < nb4; i += 4) {
      PROC2(r0, r1, i);
      PROC2(r2, r3, i + 2);
    }
    // tail (<=3 edges): ring reg t holds edge nb4+t
    if (nb4 + 0 < nb) TAIL2(r0, nb4 + 0);
    if (nb4 + 1 < nb) TAIL2(r1, nb4 + 1);
    if (nb4 + 2 < nb) TAIL2(r2, nb4 + 2);
  }
#undef LOADR
#undef DOT2
#undef SMUP2
#undef PROC2
#undef TAIL2

  const float inv = (end > beg) ? 1.f / ssum : 0.f;
  u32 ow[PAIRS];
#pragma unroll
  for (int k = 0; k < PAIRS; ++k) {
    float o0 = accp[k][0] * inv + bias[j0 + 2 * k];
    float o1 = accp[k][1] * inv + bias[j0 + 2 * k + 1];
    hbf16 h0 = __float2bfloat16(o0), h1 = __float2bfloat16(o1);
    ow[k] = (u32)(*(unsigned short*)&h0) | ((u32)(*(unsigned short*)&h1) << 16);
  }
  *(uint4*)((u32*)((short*)out + (size_t)d * HC + j0)) = *(const uint4*)ow;
  if ((lane & 31) == 0) msbuf[d * 4 + hgrp] = make_float2(m_run, ssum);
}

extern "C" void kernel_launch(void* const* d_in, const int* in_sizes, int n_in,
                              void* d_out, int out_size, void* d_ws, size_t ws_size,
                              hipStream_t stream) {
  const float* x    = (const float*)d_in[0];
  const int*   ei   = (const int*)d_in[1];
  const float* ea   = (const float*)d_in[2];
  const float* W1l  = (const float*)d_in[3];
  const float* b1l  = (const float*)d_in[4];
  const float* W1r  = (const float*)d_in[5];
  const float* b1r  = (const float*)d_in[6];
  const float* W1e  = (const float*)d_in[7];
  const float* att1 = (const float*)d_in[8];
  const float* bias1= (const float*)d_in[9];
  const float* W2l  = (const float*)d_in[10];
  const float* b2l  = (const float*)d_in[11];
  const float* W2r  = (const float*)d_in[12];
  const float* b2r  = (const float*)d_in[13];
  const float* W2e  = (const float*)d_in[14];
  const float* att2 = (const float*)d_in[15];
  const float* bias2= (const float*)d_in[16];
  const float* Wp   = (const float*)d_in[17];
  const float* bp   = (const float*)d_in[18];

  const int N = in_sizes[0] / 256;  // 10000
  const int E = in_sizes[1] / 2;    // 320000
  const int* srcI = ei;
  const int* dstI = ei + E;

  // workspace (~68 MB)
  float* wsf = (float*)d_ws;
  float2* msbuf = (float2*)wsf;                   // 4N float2
  int*   P    = (int*)(wsf + (size_t)8 * N);      // N
  int*   part = P + N;                            // 256 (scan partials)
  int*   perm = part + 256;                       // E
  hbf16* xb   = (hbf16*)(perm + E);               // N*256 (x bf16)
  hbf16* xlr  = xb + (size_t)N * 256;             // N*2048 (merged xl|xr; L1 uses N*512)
  hbf16* ho   = xlr + (size_t)N * 2048;           // N*1024 (h first N*256, then out2)
  hbf16* W1lt = ho + (size_t)N * 1024;            // 256*256  (W1rt adjacent)
  hbf16* W1rt = W1lt + 256 * 256;
  hbf16* W2lt = W1rt + 256 * 256;                 // 1024*256 (W2rt adjacent)
  hbf16* W2rt = W2lt + 1024 * 256;
  hbf16* Wpt  = W2rt + 1024 * 256;                // 256*1024

  float* yout = (float*)d_out;                    // N*256
  float* alpha_out = yout + (size_t)N * 256;      // E*4

  const int eB = (E + 255) / 256;                 // 1250
  const int sB = (N + 255) / 256;                 // 40 scan blocks
  const int gy = (N + 127) / 128;                 // 79 GEMM row-blocks

  // 1. memset P
  hipMemsetAsync(P, 0, (size_t)N * 4, stream);

  // 2. hist + cvt(x) + weight transposes (one launch)
  const int nx = N * 256;
  const int nxB = (nx / 4 + 255) / 256;
  prep_hist_kernel<<<eB + nxB + 896, 256, 0, stream>>>(
      dstI, P, E, eB, x, xb, nx, nxB, W1l, W1lt, W1r, W1rt, W2l, W2lt, W2r, W2rt,
      Wp, Wpt);

  // 3-4. CSR scan (2 launches)
  scan_sum_kernel<<<sB, 256, 0, stream>>>(P, part, N);
  scan_apply_kernel<<<sB, 256, 0, stream>>>(P, part, N, sB);

  // 5. scatter + GEMM1 (merged; deps: scan_apply for scatter, prep for GEMM)
  scatter_gemm1_kernel<<<eB + 4 * gy, 256, 0, stream>>>(
      dstI, P, perm, E, eB, xb, W1lt, b1l, b1r, xlr, N);

  // 6. fused layer 1
  fused_gat_l1_kernel<<<(N + 3) / 4, 256, 0, stream>>>(
      xlr, xlr + 256, 512, ea, W1e, att1, srcI, P, perm, bias1, ho /*h*/, N);

  // 7. GEMM2 (merged l|r, N=2048)
  mfma_gemm_kernel<hbf16><<<dim3(16, gy), 256, 0, stream>>>(
      ho, W2lt, b2l, b2r, 1024, xlr, N, 2048, 256);

  // 8. fused layer 2
  fused_gat_w2_kernel<<<(N + 1) / 2, 256, 0, stream>>>(
      xlr, xlr + 1024, 2048, ea, W2e, att2, srcI, P, perm, bias2, ho /*out2*/,
      alpha_out, msbuf, N);

  // 9. alpha + projector GEMM (merged; both depend only on fused2)
  alpha_gemmp_kernel<<<2 * gy + (E * 4 + 255) / 256, 256, 0, stream>>>(
      alpha_out, msbuf, dstI, E * 4, 2 * gy, ho, Wpt, bp, yout, N);
}